// Round 11
// baseline (720.596 us; speedup 1.0000x reference)
//
#include <hip/hip_runtime.h>

// ---------------------------------------------------------------------------
// LightGCN on MI355X — round 10.
//  - spmm_final64: ALL last-use streams (z0/z1 row reads, ci, rp) are
//    nontemporal loads so the hot 128MB z2 gather source stays L3-resident
//    (R9: FETCH 445MB vs ~290 compulsory => ~165MB z2 refetch from stream
//    eviction). out stores already NT.
//  - deg_rank: 2 edges/thread (int2 loads, 4 outstanding atomics) for more
//    memory-level parallelism at 0.85 TB/s random-granule rate.
//  - Rest unchanged from R9: W=64 full-128B-line bf16 gather rows, CSR via
//    deg_rank + XCD-sliced atomic-free fill, fused final layer + epilogue.
// ---------------------------------------------------------------------------

#define BLK 256
#define SCAN_CHUNK 2048
#define FILL_EPB 2048     // edges per fill block chunk

typedef unsigned int u32;
typedef unsigned char u8;
typedef float __attribute__((ext_vector_type(4))) f32x4;
typedef u32   __attribute__((ext_vector_type(4))) u32x4;

static inline int nblk(long long total) { return (int)((total + BLK - 1) / BLK); }

// round-to-nearest-even pack of two f32 into bf16x2
__device__ inline u32 pack_bf2(float lo, float hi) {
    u32 a = __float_as_uint(lo);
    u32 b = __float_as_uint(hi);
    a = a + 0x7fffu + ((a >> 16) & 1u);
    b = b + 0x7fffu + ((b >> 16) & 1u);
    return (a >> 16) | (b & 0xffff0000u);
}

__device__ inline void unpack_acc(uint4 w, float* a) {
    a[0] += __uint_as_float(w.x << 16);
    a[1] += __uint_as_float(w.x & 0xffff0000u);
    a[2] += __uint_as_float(w.y << 16);
    a[3] += __uint_as_float(w.y & 0xffff0000u);
    a[4] += __uint_as_float(w.z << 16);
    a[5] += __uint_as_float(w.z & 0xffff0000u);
    a[6] += __uint_as_float(w.w << 16);
    a[7] += __uint_as_float(w.w & 0xffff0000u);
}

__device__ inline void unpack8v(u32x4 w, float* a) {
    a[0] = __uint_as_float(w[0] << 16);
    a[1] = __uint_as_float(w[0] & 0xffff0000u);
    a[2] = __uint_as_float(w[1] << 16);
    a[3] = __uint_as_float(w[1] & 0xffff0000u);
    a[4] = __uint_as_float(w[2] << 16);
    a[5] = __uint_as_float(w[2] & 0xffff0000u);
    a[6] = __uint_as_float(w[3] << 16);
    a[7] = __uint_as_float(w[3] & 0xffff0000u);
}

// ---- degree (u8-packed) + per-edge rank, 2 edges/thread -------------------
__global__ void deg_rank_kernel(const int* __restrict__ uid,
                                const int* __restrict__ iid,
                                int E, int n_users,
                                u32* __restrict__ degw,   // u8 counters, word-packed
                                u32* __restrict__ rank2) {
    int t = blockIdx.x * blockDim.x + threadIdx.x;
    int e0 = t * 2;
    if (e0 >= E) return;
    if (e0 + 1 < E) {
        int2 uu = *(const int2*)(uid + e0);
        int2 ii = *(const int2*)(iid + e0);
        u32 ua = (u32)uu.x, ub = (u32)uu.y;
        u32 ia = (u32)(n_users + ii.x), ib = (u32)(n_users + ii.y);
        u32 sua = 8u * (ua & 3u), sub = 8u * (ub & 3u);
        u32 sia = 8u * (ia & 3u), sib = 8u * (ib & 3u);
        u32 r0a = atomicAdd(&degw[ua >> 2], 1u << sua);
        u32 r1a = atomicAdd(&degw[ia >> 2], 1u << sia);
        u32 r0b = atomicAdd(&degw[ub >> 2], 1u << sub);
        u32 r1b = atomicAdd(&degw[ib >> 2], 1u << sib);
        rank2[e0]     = ((r0a >> sua) & 0xffu) | (((r1a >> sia) & 0xffu) << 16);
        rank2[e0 + 1] = ((r0b >> sub) & 0xffu) | (((r1b >> sib) & 0xffu) << 16);
    } else {
        u32 u  = (u32)uid[e0];
        u32 iN = (u32)(n_users + iid[e0]);
        u32 su = 8u * (u & 3u), si = 8u * (iN & 3u);
        u32 r0 = atomicAdd(&degw[u >> 2],  1u << su);
        u32 r1 = atomicAdd(&degw[iN >> 2], 1u << si);
        rank2[e0] = ((r0 >> su) & 0xffu) | (((r1 >> si) & 0xffu) << 16);
    }
}

__global__ void dinv_kernel(const u8* __restrict__ deg8,
                            float* __restrict__ dinv, int n_nodes) {
    int t = blockIdx.x * blockDim.x + threadIdx.x;
    if (t < n_nodes) dinv[t] = rsqrtf((float)deg8[t] + 1e-8f);
}

// ---- prefix scan over u8 degrees: rp[i+1] = incl_sum(deg8[0..i]) ---------
__global__ void scan1_kernel(const u8* __restrict__ deg8,
                             u32* __restrict__ rp, u32* __restrict__ bsum, int n) {
    __shared__ u32 ts[256];
    int tid = threadIdx.x;
    int base = blockIdx.x * SCAN_CHUNK + tid * 8;
    u32 v[8];
    u32 s = 0;
    #pragma unroll
    for (int i = 0; i < 8; ++i) {
        v[i] = (base + i < n) ? (u32)deg8[base + i] : 0u;
        s += v[i];
    }
    ts[tid] = s;
    __syncthreads();
    for (int off = 1; off < 256; off <<= 1) {
        u32 a = (tid >= off) ? ts[tid - off] : 0u;
        __syncthreads();
        ts[tid] += a;
        __syncthreads();
    }
    u32 run = (tid > 0) ? ts[tid - 1] : 0u;
    #pragma unroll
    for (int i = 0; i < 8; ++i) {
        run += v[i];
        if (base + i < n) rp[base + i + 1] = run;
    }
    if (tid == 255) bsum[blockIdx.x] = ts[255];
}

__global__ void scan2_kernel(u32* __restrict__ bsum, int nb) {
    __shared__ u32 s[1024];
    int tid = threadIdx.x;
    s[tid] = (tid < nb) ? bsum[tid] : 0u;
    __syncthreads();
    for (int off = 1; off < 1024; off <<= 1) {
        u32 a = (tid >= off) ? s[tid - off] : 0u;
        __syncthreads();
        s[tid] += a;
        __syncthreads();
    }
    if (tid < nb) bsum[tid] = (tid == 0) ? 0u : s[tid - 1];
}

__global__ void scan3_kernel(u32* __restrict__ rp,
                             const u32* __restrict__ bsum, int n) {
    int t = blockIdx.x * blockDim.x + threadIdx.x;
    if (t < n) rp[t + 1] += bsum[t / SCAN_CHUNK];
    if (t == 0) rp[0] = 0u;
}

// ---- atomic-free, XCD-sliced CSR fill ------------------------------------
__global__ void fill_sliced_kernel(const int* __restrict__ uid,
                                   const int* __restrict__ iid,
                                   const u32* __restrict__ rank2,
                                   const u32* __restrict__ rp,
                                   int E, int n_users, int shift,
                                   int* __restrict__ ci) {
    int slice = blockIdx.x & 7;
    int chunk = blockIdx.x >> 3;
    int e0   = chunk * FILL_EPB;
    int eend = min(E, e0 + FILL_EPB);
    for (int e = e0 + threadIdx.x; e < eend; e += BLK) {
        int u  = uid[e];
        int iN = n_users + iid[e];
        u32 rr = rank2[e];
        if ((u >> shift) == slice)  ci[rp[u]  + (rr & 0xffffu)] = iN;
        if ((iN >> shift) == slice) ci[rp[iN] + (rr >> 16)]     = u;
    }
}

// ---- z0 = dinv * emb, bf16 [node][64] = 8 uint4 per 128B row --------------
__global__ void z0_full_kernel(const f32x4* __restrict__ uemb,
                               const f32x4* __restrict__ iemb,
                               const float* __restrict__ dinv,
                               uint4* __restrict__ z0,
                               int n_users, int n_nodes) {
    long long t = (long long)blockIdx.x * blockDim.x + threadIdx.x;
    if (t >= (long long)n_nodes * 8) return;
    int row = (int)(t >> 3);
    int j   = (int)(t & 7);
    const f32x4* src = (row < n_users)
                           ? uemb + (size_t)row * 16 + j * 2
                           : iemb + (size_t)(row - n_users) * 16 + j * 2;
    f32x4 p = __builtin_nontemporal_load(src);
    f32x4 q = __builtin_nontemporal_load(src + 1);
    float w = dinv[row];
    uint4 o;
    o.x = pack_bf2(w * p.x, w * p.y);
    o.y = pack_bf2(w * p.z, w * p.w);
    o.z = pack_bf2(w * q.x, w * q.y);
    o.w = pack_bf2(w * q.z, w * q.w);
    z0[(size_t)row * 8 + j] = o;
}

// ---- middle layers: dst = bf16( dinv^2 * sum_{c} src[c] ), 128B rows ------
__global__ void spmm_mid64(const u32* __restrict__ rp,
                           const int* __restrict__ ci,
                           const float* __restrict__ dinv,
                           const uint4* __restrict__ src,
                           uint4* __restrict__ dst, int n_nodes) {
    long long t = (long long)blockIdx.x * blockDim.x + threadIdx.x;
    int row = (int)(t >> 3);
    if (row >= n_nodes) return;
    int j = (int)(t & 7);
    const uint4* sp = src + j;
    u32 k = rp[row], end = rp[row + 1];
    float a[8] = {0.f, 0.f, 0.f, 0.f, 0.f, 0.f, 0.f, 0.f};
    for (; k + 3 < end; k += 4) {
        int c0 = ci[k], c1 = ci[k + 1], c2 = ci[k + 2], c3 = ci[k + 3];
        uint4 w0 = sp[(size_t)c0 * 8];
        uint4 w1 = sp[(size_t)c1 * 8];
        uint4 w2 = sp[(size_t)c2 * 8];
        uint4 w3 = sp[(size_t)c3 * 8];
        unpack_acc(w0, a); unpack_acc(w1, a);
        unpack_acc(w2, a); unpack_acc(w3, a);
    }
    for (; k < end; ++k) {
        uint4 w0 = sp[(size_t)ci[k] * 8];
        unpack_acc(w0, a);
    }
    float dr = dinv[row];
    float s = dr * dr;
    uint4 o;
    o.x = pack_bf2(s * a[0], s * a[1]);
    o.y = pack_bf2(s * a[2], s * a[3]);
    o.z = pack_bf2(s * a[4], s * a[5]);
    o.w = pack_bf2(s * a[6], s * a[7]);
    dst[(size_t)row * 8 + j] = o;
}

// ---- layer 3 + fused epilogue -------------------------------------------
// All last-use streams (ci, rp, z0/z1 rows) are NT loads so the hot z2
// gather source keeps L3 residency; out stores NT.
__global__ void spmm_final64(const u32* __restrict__ rp,
                             const int* __restrict__ ci,
                             const float* __restrict__ dinv,
                             const uint4* __restrict__ z2,
                             const u32x4* __restrict__ z1,
                             const u32x4* __restrict__ z0,
                             f32x4* __restrict__ out, int n_nodes) {
    long long t = (long long)blockIdx.x * blockDim.x + threadIdx.x;
    int row = (int)(t >> 3);
    if (row >= n_nodes) return;
    int j = (int)(t & 7);
    const uint4* sp = z2 + j;
    u32 k   = __builtin_nontemporal_load(rp + row);
    u32 end = __builtin_nontemporal_load(rp + row + 1);
    float a[8] = {0.f, 0.f, 0.f, 0.f, 0.f, 0.f, 0.f, 0.f};
    for (; k + 3 < end; k += 4) {
        int c0 = __builtin_nontemporal_load(ci + k);
        int c1 = __builtin_nontemporal_load(ci + k + 1);
        int c2 = __builtin_nontemporal_load(ci + k + 2);
        int c3 = __builtin_nontemporal_load(ci + k + 3);
        uint4 w0 = sp[(size_t)c0 * 8];
        uint4 w1 = sp[(size_t)c1 * 8];
        uint4 w2 = sp[(size_t)c2 * 8];
        uint4 w3 = sp[(size_t)c3 * 8];
        unpack_acc(w0, a); unpack_acc(w1, a);
        unpack_acc(w2, a); unpack_acc(w3, a);
    }
    for (; k < end; ++k) {
        int c0 = __builtin_nontemporal_load(ci + k);
        uint4 w0 = sp[(size_t)c0 * 8];
        unpack_acc(w0, a);
    }
    float dr = dinv[row];
    float inv = 1.0f / dr;

    float v0[8], v1[8], v2[8];
    u32x4 r0 = __builtin_nontemporal_load(z0 + (size_t)row * 8 + j);
    u32x4 r1 = __builtin_nontemporal_load(z1 + (size_t)row * 8 + j);
    unpack8v(r0, v0);
    unpack8v(r1, v1);
    uint4 r2 = z2[(size_t)row * 8 + j];   // hot buffer: normal (cached) read
    u32x4 r2v = {r2.x, r2.y, r2.z, r2.w};
    unpack8v(r2v, v2);

    float r[8];
    #pragma unroll
    for (int i = 0; i < 8; ++i)
        r[i] = 0.25f * ((v0[i] + v1[i] + v2[i]) * inv + dr * a[i]);

    size_t ob = (size_t)row * 16 + j * 2;
    f32x4 lo = {r[0], r[1], r[2], r[3]};
    f32x4 hi = {r[4], r[5], r[6], r[7]};
    __builtin_nontemporal_store(lo, out + ob);
    __builtin_nontemporal_store(hi, out + ob + 1);
}

// ---------------------------------------------------------------------------
extern "C" void kernel_launch(void* const* d_in, const int* in_sizes, int n_in,
                              void* d_out, int out_size, void* d_ws, size_t ws_size,
                              hipStream_t stream) {
    const float* uemb = (const float*)d_in[0];
    const float* iemb = (const float*)d_in[1];
    const int*   uid  = (const int*)d_in[2];
    const int*   iid  = (const int*)d_in[3];

    const int d = 64;
    int n_users = in_sizes[0] / d;
    int n_items = in_sizes[1] / d;
    int E       = in_sizes[2];
    int n_nodes = n_users + n_items;
    long long nnz = 2LL * E;

    auto align256 = [](size_t x) { return (x + 255) & ~(size_t)255; };
    size_t deg_b  = align256((size_t)n_nodes + 4);       // u8 counters
    size_t rp_b   = align256((size_t)(n_nodes + 1) * 4);
    size_t dinv_b = align256((size_t)n_nodes * 4);
    size_t ci_b   = align256((size_t)nnz * 4);
    size_t rk_b   = align256((size_t)E * 4);
    size_t bs_b   = align256(4096 * 4);
    size_t z_b    = align256((size_t)n_nodes * 128);     // 64 bf16 per row

    char* p = (char*)d_ws;
    u32*   degw  = (u32*)p;    p += deg_b;
    u32*   rp    = (u32*)p;    p += rp_b;
    float* dinv  = (float*)p;  p += dinv_b;
    int*   ci    = (int*)p;    p += ci_b;
    u32*   rank2 = (u32*)p;    p += rk_b;
    u32*   bsum  = (u32*)p;    p += bs_b;
    uint4* z0    = (uint4*)p;  p += z_b;
    uint4* z1    = (uint4*)p;  p += z_b;
    uint4* z2    = (uint4*)p;

    // node-range slice shift for fill: slice = row >> shift in [0,8)
    int shift = 0;
    while (((n_nodes - 1) >> shift) >= 8) shift++;

    // ---- degrees (u8, + per-edge ranks), dinv ----
    hipMemsetAsync(degw, 0, (size_t)n_nodes + 4, stream);
    deg_rank_kernel<<<nblk((E + 1) / 2), BLK, 0, stream>>>(
        uid, iid, E, n_users, degw, rank2);
    dinv_kernel<<<nblk(n_nodes), BLK, 0, stream>>>((const u8*)degw, dinv, n_nodes);

    // ---- prefix scan deg8 -> rp ----
    int nb = (n_nodes + SCAN_CHUNK - 1) / SCAN_CHUNK;
    scan1_kernel<<<nb, 256, 0, stream>>>((const u8*)degw, rp, bsum, n_nodes);
    scan2_kernel<<<1, 1024, 0, stream>>>(bsum, nb);
    scan3_kernel<<<nblk(n_nodes), BLK, 0, stream>>>(rp, bsum, n_nodes);

    // ---- atomic-free XCD-sliced CSR fill ----
    int nchunks = (E + FILL_EPB - 1) / FILL_EPB;
    fill_sliced_kernel<<<nchunks * 8, BLK, 0, stream>>>(
        uid, iid, rank2, rp, E, n_users, shift, ci);

    // ---- full-width bf16 pipeline: z0, two mids, fused final ----
    long long nt = (long long)n_nodes * 8;
    z0_full_kernel<<<nblk(nt), BLK, 0, stream>>>(
        (const f32x4*)uemb, (const f32x4*)iemb, dinv, z0, n_users, n_nodes);
    spmm_mid64<<<nblk(nt), BLK, 0, stream>>>(rp, ci, dinv, z0, z1, n_nodes);
    spmm_mid64<<<nblk(nt), BLK, 0, stream>>>(rp, ci, dinv, z1, z2, n_nodes);
    spmm_final64<<<nblk(nt), BLK, 0, stream>>>(rp, ci, dinv, z2,
                                               (const u32x4*)z1, (const u32x4*)z0,
                                               (f32x4*)d_out, n_nodes);
}

// Round 12
// 719.757 us; speedup vs baseline: 1.0012x; 1.0012x over previous
//
#include <hip/hip_runtime.h>

// ---------------------------------------------------------------------------
// LightGCN on MI355X — round 11.
//  - R10 post-mortem: NT loads in final64 HURT (FETCH 445->469MB) -> reverted.
//    deg_rank 2-edge unrolling null -> reverted. Both now at structural
//    floors (atomic-op rate / L3 line service rate).
//  - NEW: fused_deg_conv kernel. deg_rank (atomic-op-bound, 157us) and the
//    z0 bf16 conversion (BW-bound, ~55us) are independent if z0 stores
//    UNSCALED emb; dinv is folded into layer-1's gather (dinv[c] is a 4B
//    L3-resident broadcast shared by the row's 8 lanes). Block-range
//    partitioned single kernel => the two passes overlap on one stream.
//  - Rest = R9: W=64 full-128B-line rows, XCD-sliced fill, pre-scaled bf16
//    recurrence from layer 1 onward, fused final layer + epilogue (NT stores).
// ---------------------------------------------------------------------------

#define BLK 256
#define SCAN_CHUNK 2048
#define FILL_EPB 2048     // edges per fill block chunk

typedef unsigned int u32;
typedef unsigned char u8;
typedef float __attribute__((ext_vector_type(4))) f32x4;

static inline int nblk(long long total) { return (int)((total + BLK - 1) / BLK); }

// round-to-nearest-even pack of two f32 into bf16x2
__device__ inline u32 pack_bf2(float lo, float hi) {
    u32 a = __float_as_uint(lo);
    u32 b = __float_as_uint(hi);
    a = a + 0x7fffu + ((a >> 16) & 1u);
    b = b + 0x7fffu + ((b >> 16) & 1u);
    return (a >> 16) | (b & 0xffff0000u);
}

__device__ inline void unpack_acc(uint4 w, float* a) {
    a[0] += __uint_as_float(w.x << 16);
    a[1] += __uint_as_float(w.x & 0xffff0000u);
    a[2] += __uint_as_float(w.y << 16);
    a[3] += __uint_as_float(w.y & 0xffff0000u);
    a[4] += __uint_as_float(w.z << 16);
    a[5] += __uint_as_float(w.z & 0xffff0000u);
    a[6] += __uint_as_float(w.w << 16);
    a[7] += __uint_as_float(w.w & 0xffff0000u);
}

__device__ inline void unpack_acc_s(uint4 w, float s, float* a) {
    a[0] += s * __uint_as_float(w.x << 16);
    a[1] += s * __uint_as_float(w.x & 0xffff0000u);
    a[2] += s * __uint_as_float(w.y << 16);
    a[3] += s * __uint_as_float(w.y & 0xffff0000u);
    a[4] += s * __uint_as_float(w.z << 16);
    a[5] += s * __uint_as_float(w.z & 0xffff0000u);
    a[6] += s * __uint_as_float(w.w << 16);
    a[7] += s * __uint_as_float(w.w & 0xffff0000u);
}

__device__ inline void unpack8(uint4 w, float* a) {
    a[0] = __uint_as_float(w.x << 16);
    a[1] = __uint_as_float(w.x & 0xffff0000u);
    a[2] = __uint_as_float(w.y << 16);
    a[3] = __uint_as_float(w.y & 0xffff0000u);
    a[4] = __uint_as_float(w.z << 16);
    a[5] = __uint_as_float(w.z & 0xffff0000u);
    a[6] = __uint_as_float(w.w << 16);
    a[7] = __uint_as_float(w.w & 0xffff0000u);
}

// ---- fused: degree+rank atomics (blocks < nblk_deg) || bf16(emb) (rest) ---
__global__ void fused_deg_conv(const int* __restrict__ uid,
                               const int* __restrict__ iid,
                               int E, int n_users,
                               u32* __restrict__ degw,
                               u32* __restrict__ rank2,
                               const f32x4* __restrict__ uemb,
                               const f32x4* __restrict__ iemb,
                               uint4* __restrict__ z0,
                               int n_nodes, int nblk_deg) {
    if ((int)blockIdx.x < nblk_deg) {
        int t = blockIdx.x * BLK + threadIdx.x;
        if (t < E) {
            u32 u  = (u32)uid[t];
            u32 iN = (u32)(n_users + iid[t]);
            u32 su = 8u * (u & 3u), si = 8u * (iN & 3u);
            u32 r0 = atomicAdd(&degw[u >> 2],  1u << su);
            u32 r1 = atomicAdd(&degw[iN >> 2], 1u << si);
            rank2[t] = ((r0 >> su) & 0xffu) | (((r1 >> si) & 0xffu) << 16);
        }
    } else {
        long long t = (long long)(blockIdx.x - nblk_deg) * BLK + threadIdx.x;
        if (t >= (long long)n_nodes * 8) return;
        int row = (int)(t >> 3);
        int j   = (int)(t & 7);
        const f32x4* src = (row < n_users)
                               ? uemb + (size_t)row * 16 + j * 2
                               : iemb + (size_t)(row - n_users) * 16 + j * 2;
        f32x4 p = __builtin_nontemporal_load(src);
        f32x4 q = __builtin_nontemporal_load(src + 1);
        uint4 o;
        o.x = pack_bf2(p.x, p.y);
        o.y = pack_bf2(p.z, p.w);
        o.z = pack_bf2(q.x, q.y);
        o.w = pack_bf2(q.z, q.w);
        z0[(size_t)row * 8 + j] = o;   // UNSCALED bf16 emb
    }
}

__global__ void dinv_kernel(const u8* __restrict__ deg8,
                            float* __restrict__ dinv, int n_nodes) {
    int t = blockIdx.x * blockDim.x + threadIdx.x;
    if (t < n_nodes) dinv[t] = rsqrtf((float)deg8[t] + 1e-8f);
}

// ---- prefix scan over u8 degrees: rp[i+1] = incl_sum(deg8[0..i]) ---------
__global__ void scan1_kernel(const u8* __restrict__ deg8,
                             u32* __restrict__ rp, u32* __restrict__ bsum, int n) {
    __shared__ u32 ts[256];
    int tid = threadIdx.x;
    int base = blockIdx.x * SCAN_CHUNK + tid * 8;
    u32 v[8];
    u32 s = 0;
    #pragma unroll
    for (int i = 0; i < 8; ++i) {
        v[i] = (base + i < n) ? (u32)deg8[base + i] : 0u;
        s += v[i];
    }
    ts[tid] = s;
    __syncthreads();
    for (int off = 1; off < 256; off <<= 1) {
        u32 a = (tid >= off) ? ts[tid - off] : 0u;
        __syncthreads();
        ts[tid] += a;
        __syncthreads();
    }
    u32 run = (tid > 0) ? ts[tid - 1] : 0u;
    #pragma unroll
    for (int i = 0; i < 8; ++i) {
        run += v[i];
        if (base + i < n) rp[base + i + 1] = run;
    }
    if (tid == 255) bsum[blockIdx.x] = ts[255];
}

__global__ void scan2_kernel(u32* __restrict__ bsum, int nb) {
    __shared__ u32 s[1024];
    int tid = threadIdx.x;
    s[tid] = (tid < nb) ? bsum[tid] : 0u;
    __syncthreads();
    for (int off = 1; off < 1024; off <<= 1) {
        u32 a = (tid >= off) ? s[tid - off] : 0u;
        __syncthreads();
        s[tid] += a;
        __syncthreads();
    }
    if (tid < nb) bsum[tid] = (tid == 0) ? 0u : s[tid - 1];
}

__global__ void scan3_kernel(u32* __restrict__ rp,
                             const u32* __restrict__ bsum, int n) {
    int t = blockIdx.x * blockDim.x + threadIdx.x;
    if (t < n) rp[t + 1] += bsum[t / SCAN_CHUNK];
    if (t == 0) rp[0] = 0u;
}

// ---- atomic-free, XCD-sliced CSR fill ------------------------------------
__global__ void fill_sliced_kernel(const int* __restrict__ uid,
                                   const int* __restrict__ iid,
                                   const u32* __restrict__ rank2,
                                   const u32* __restrict__ rp,
                                   int E, int n_users, int shift,
                                   int* __restrict__ ci) {
    int slice = blockIdx.x & 7;
    int chunk = blockIdx.x >> 3;
    int e0   = chunk * FILL_EPB;
    int eend = min(E, e0 + FILL_EPB);
    for (int e = e0 + threadIdx.x; e < eend; e += BLK) {
        int u  = uid[e];
        int iN = n_users + iid[e];
        u32 rr = rank2[e];
        if ((u >> shift) == slice)  ci[rp[u]  + (rr & 0xffffu)] = iN;
        if ((iN >> shift) == slice) ci[rp[iN] + (rr >> 16)]     = u;
    }
}

// ---- layer 1: z1 = bf16( dinv_r^2 * sum_c dinv[c] * z0'[c] ) --------------
// z0' is unscaled; dinv[c] is a 4B L3-resident load, identical across the
// row's 8 lanes (broadcast).
__global__ void spmm_first64(const u32* __restrict__ rp,
                             const int* __restrict__ ci,
                             const float* __restrict__ dinv,
                             const uint4* __restrict__ z0p,
                             uint4* __restrict__ dst, int n_nodes) {
    long long t = (long long)blockIdx.x * blockDim.x + threadIdx.x;
    int row = (int)(t >> 3);
    if (row >= n_nodes) return;
    int j = (int)(t & 7);
    const uint4* sp = z0p + j;
    u32 k = rp[row], end = rp[row + 1];
    float a[8] = {0.f, 0.f, 0.f, 0.f, 0.f, 0.f, 0.f, 0.f};
    for (; k + 3 < end; k += 4) {
        int c0 = ci[k], c1 = ci[k + 1], c2 = ci[k + 2], c3 = ci[k + 3];
        uint4 w0 = sp[(size_t)c0 * 8];
        uint4 w1 = sp[(size_t)c1 * 8];
        uint4 w2 = sp[(size_t)c2 * 8];
        uint4 w3 = sp[(size_t)c3 * 8];
        float d0 = dinv[c0], d1 = dinv[c1], d2 = dinv[c2], d3 = dinv[c3];
        unpack_acc_s(w0, d0, a); unpack_acc_s(w1, d1, a);
        unpack_acc_s(w2, d2, a); unpack_acc_s(w3, d3, a);
    }
    for (; k < end; ++k) {
        int c0 = ci[k];
        uint4 w0 = sp[(size_t)c0 * 8];
        unpack_acc_s(w0, dinv[c0], a);
    }
    float dr = dinv[row];
    float s = dr * dr;
    uint4 o;
    o.x = pack_bf2(s * a[0], s * a[1]);
    o.y = pack_bf2(s * a[2], s * a[3]);
    o.z = pack_bf2(s * a[4], s * a[5]);
    o.w = pack_bf2(s * a[6], s * a[7]);
    dst[(size_t)row * 8 + j] = o;
}

// ---- middle layer: dst = bf16( dinv^2 * sum_c src[c] ), 128B rows ---------
__global__ void spmm_mid64(const u32* __restrict__ rp,
                           const int* __restrict__ ci,
                           const float* __restrict__ dinv,
                           const uint4* __restrict__ src,
                           uint4* __restrict__ dst, int n_nodes) {
    long long t = (long long)blockIdx.x * blockDim.x + threadIdx.x;
    int row = (int)(t >> 3);
    if (row >= n_nodes) return;
    int j = (int)(t & 7);
    const uint4* sp = src + j;
    u32 k = rp[row], end = rp[row + 1];
    float a[8] = {0.f, 0.f, 0.f, 0.f, 0.f, 0.f, 0.f, 0.f};
    for (; k + 3 < end; k += 4) {
        int c0 = ci[k], c1 = ci[k + 1], c2 = ci[k + 2], c3 = ci[k + 3];
        uint4 w0 = sp[(size_t)c0 * 8];
        uint4 w1 = sp[(size_t)c1 * 8];
        uint4 w2 = sp[(size_t)c2 * 8];
        uint4 w3 = sp[(size_t)c3 * 8];
        unpack_acc(w0, a); unpack_acc(w1, a);
        unpack_acc(w2, a); unpack_acc(w3, a);
    }
    for (; k < end; ++k) {
        uint4 w0 = sp[(size_t)ci[k] * 8];
        unpack_acc(w0, a);
    }
    float dr = dinv[row];
    float s = dr * dr;
    uint4 o;
    o.x = pack_bf2(s * a[0], s * a[1]);
    o.y = pack_bf2(s * a[2], s * a[3]);
    o.z = pack_bf2(s * a[4], s * a[5]);
    o.w = pack_bf2(s * a[6], s * a[7]);
    dst[(size_t)row * 8 + j] = o;
}

// ---- layer 3 + fused epilogue (normal loads, NT stores) -------------------
// out = 0.25*( z0'[row] + (z1[row]+z2[row])/dinv + dinv * sum_c z2[c] )
__global__ void spmm_final64(const u32* __restrict__ rp,
                             const int* __restrict__ ci,
                             const float* __restrict__ dinv,
                             const uint4* __restrict__ z2,
                             const uint4* __restrict__ z1,
                             const uint4* __restrict__ z0,
                             f32x4* __restrict__ out, int n_nodes) {
    long long t = (long long)blockIdx.x * blockDim.x + threadIdx.x;
    int row = (int)(t >> 3);
    if (row >= n_nodes) return;
    int j = (int)(t & 7);
    const uint4* sp = z2 + j;
    u32 k = rp[row], end = rp[row + 1];
    float a[8] = {0.f, 0.f, 0.f, 0.f, 0.f, 0.f, 0.f, 0.f};
    for (; k + 3 < end; k += 4) {
        int c0 = ci[k], c1 = ci[k + 1], c2 = ci[k + 2], c3 = ci[k + 3];
        uint4 w0 = sp[(size_t)c0 * 8];
        uint4 w1 = sp[(size_t)c1 * 8];
        uint4 w2 = sp[(size_t)c2 * 8];
        uint4 w3 = sp[(size_t)c3 * 8];
        unpack_acc(w0, a); unpack_acc(w1, a);
        unpack_acc(w2, a); unpack_acc(w3, a);
    }
    for (; k < end; ++k) {
        uint4 w0 = sp[(size_t)ci[k] * 8];
        unpack_acc(w0, a);
    }
    float dr = dinv[row];
    float inv = 1.0f / dr;

    float v0[8], v1[8], v2[8];
    unpack8(z0[(size_t)row * 8 + j], v0);   // unscaled emb term
    unpack8(z1[(size_t)row * 8 + j], v1);
    unpack8(z2[(size_t)row * 8 + j], v2);

    float r[8];
    #pragma unroll
    for (int i = 0; i < 8; ++i)
        r[i] = 0.25f * (v0[i] + (v1[i] + v2[i]) * inv + dr * a[i]);

    size_t ob = (size_t)row * 16 + j * 2;
    f32x4 lo = {r[0], r[1], r[2], r[3]};
    f32x4 hi = {r[4], r[5], r[6], r[7]};
    __builtin_nontemporal_store(lo, out + ob);
    __builtin_nontemporal_store(hi, out + ob + 1);
}

// ---------------------------------------------------------------------------
extern "C" void kernel_launch(void* const* d_in, const int* in_sizes, int n_in,
                              void* d_out, int out_size, void* d_ws, size_t ws_size,
                              hipStream_t stream) {
    const float* uemb = (const float*)d_in[0];
    const float* iemb = (const float*)d_in[1];
    const int*   uid  = (const int*)d_in[2];
    const int*   iid  = (const int*)d_in[3];

    const int d = 64;
    int n_users = in_sizes[0] / d;
    int n_items = in_sizes[1] / d;
    int E       = in_sizes[2];
    int n_nodes = n_users + n_items;
    long long nnz = 2LL * E;

    auto align256 = [](size_t x) { return (x + 255) & ~(size_t)255; };
    size_t deg_b  = align256((size_t)n_nodes + 4);       // u8 counters
    size_t rp_b   = align256((size_t)(n_nodes + 1) * 4);
    size_t dinv_b = align256((size_t)n_nodes * 4);
    size_t ci_b   = align256((size_t)nnz * 4);
    size_t rk_b   = align256((size_t)E * 4);
    size_t bs_b   = align256(4096 * 4);
    size_t z_b    = align256((size_t)n_nodes * 128);     // 64 bf16 per row

    char* p = (char*)d_ws;
    u32*   degw  = (u32*)p;    p += deg_b;
    u32*   rp    = (u32*)p;    p += rp_b;
    float* dinv  = (float*)p;  p += dinv_b;
    int*   ci    = (int*)p;    p += ci_b;
    u32*   rank2 = (u32*)p;    p += rk_b;
    u32*   bsum  = (u32*)p;    p += bs_b;
    uint4* z0    = (uint4*)p;  p += z_b;
    uint4* z1    = (uint4*)p;  p += z_b;
    uint4* z2    = (uint4*)p;

    // node-range slice shift for fill: slice = row >> shift in [0,8)
    int shift = 0;
    while (((n_nodes - 1) >> shift) >= 8) shift++;

    // ---- fused: degree+rank atomics || z0' = bf16(emb) ----
    hipMemsetAsync(degw, 0, (size_t)n_nodes + 4, stream);
    int nblk_deg  = nblk(E);
    int nblk_conv = nblk((long long)n_nodes * 8);
    fused_deg_conv<<<nblk_deg + nblk_conv, BLK, 0, stream>>>(
        uid, iid, E, n_users, degw, rank2,
        (const f32x4*)uemb, (const f32x4*)iemb, z0, n_nodes, nblk_deg);
    dinv_kernel<<<nblk(n_nodes), BLK, 0, stream>>>((const u8*)degw, dinv, n_nodes);

    // ---- prefix scan deg8 -> rp ----
    int nb = (n_nodes + SCAN_CHUNK - 1) / SCAN_CHUNK;
    scan1_kernel<<<nb, 256, 0, stream>>>((const u8*)degw, rp, bsum, n_nodes);
    scan2_kernel<<<1, 1024, 0, stream>>>(bsum, nb);
    scan3_kernel<<<nblk(n_nodes), BLK, 0, stream>>>(rp, bsum, n_nodes);

    // ---- atomic-free XCD-sliced CSR fill ----
    int nchunks = (E + FILL_EPB - 1) / FILL_EPB;
    fill_sliced_kernel<<<nchunks * 8, BLK, 0, stream>>>(
        uid, iid, rank2, rp, E, n_users, shift, ci);

    // ---- SpMM chain: first (dinv-folded), mid, fused final ----
    long long nt = (long long)n_nodes * 8;
    spmm_first64<<<nblk(nt), BLK, 0, stream>>>(rp, ci, dinv, z0, z1, n_nodes);
    spmm_mid64<<<nblk(nt), BLK, 0, stream>>>(rp, ci, dinv, z1, z2, n_nodes);
    spmm_final64<<<nblk(nt), BLK, 0, stream>>>(rp, ci, dinv, z2, z1, z0,
                                               (f32x4*)d_out, n_nodes);
}

// Round 13
// 706.425 us; speedup vs baseline: 1.0201x; 1.0189x over previous
//
#include <hip/hip_runtime.h>

// ---------------------------------------------------------------------------
// LightGCN on MI355X — round 12: R9 structure restored (best measured) +
// u16-packed rank2.
//
//  R11 post-mortem: deg||conv fusion was null-to-negative (atomic+stream
//  contention, 221us vs 212 sequential) -> reverted. NT-load variants and
//  residency scheduling all measured null or worse (R6/R10).
//
//  Structure (each dispatch at a measured structural floor):
//   - deg_rank: u8-packed degree counters via device atomics; the atomicAdd
//     return IS the edge's rank (no cursor pass). ~157us = 4M atomic ops at
//     memory-side granule rate (op-count-bound, 3 variants converged).
//   - scan: 3-kernel u8 prefix -> rp.
//   - fill_sliced: atomic-free CSR fill, XCD-sliced so each node-range's ci
//     lines assemble in one L2. rank2 now u16 (2x8-bit ranks; deg<256).
//   - z0 = dinv*emb in bf16 [node][64] = one 128B line per row.
//   - spmm_mid64 x2 + spmm_final64: pull-gather, one fully-used 128B line
//     per edge; final fuses layer 3 with the 0.25*(x0+x1+x2+x3) epilogue
//     (NT stores for the 256MB out stream).
// ---------------------------------------------------------------------------

#define BLK 256
#define SCAN_CHUNK 2048
#define FILL_EPB 2048     // edges per fill block chunk

typedef unsigned int u32;
typedef unsigned short u16;
typedef unsigned char u8;
typedef float __attribute__((ext_vector_type(4))) f32x4;

static inline int nblk(long long total) { return (int)((total + BLK - 1) / BLK); }

// round-to-nearest-even pack of two f32 into bf16x2
__device__ inline u32 pack_bf2(float lo, float hi) {
    u32 a = __float_as_uint(lo);
    u32 b = __float_as_uint(hi);
    a = a + 0x7fffu + ((a >> 16) & 1u);
    b = b + 0x7fffu + ((b >> 16) & 1u);
    return (a >> 16) | (b & 0xffff0000u);
}

__device__ inline void unpack_acc(uint4 w, float* a) {
    a[0] += __uint_as_float(w.x << 16);
    a[1] += __uint_as_float(w.x & 0xffff0000u);
    a[2] += __uint_as_float(w.y << 16);
    a[3] += __uint_as_float(w.y & 0xffff0000u);
    a[4] += __uint_as_float(w.z << 16);
    a[5] += __uint_as_float(w.z & 0xffff0000u);
    a[6] += __uint_as_float(w.w << 16);
    a[7] += __uint_as_float(w.w & 0xffff0000u);
}

__device__ inline void unpack8(uint4 w, float* a) {
    a[0] = __uint_as_float(w.x << 16);
    a[1] = __uint_as_float(w.x & 0xffff0000u);
    a[2] = __uint_as_float(w.y << 16);
    a[3] = __uint_as_float(w.y & 0xffff0000u);
    a[4] = __uint_as_float(w.z << 16);
    a[5] = __uint_as_float(w.z & 0xffff0000u);
    a[6] = __uint_as_float(w.w << 16);
    a[7] = __uint_as_float(w.w & 0xffff0000u);
}

// ---- degree (u8-packed) + per-edge rank (u16: 8b|8b) ----------------------
__global__ void deg_rank_kernel(const int* __restrict__ uid,
                                const int* __restrict__ iid,
                                int E, int n_users,
                                u32* __restrict__ degw,   // u8 counters, word-packed
                                u16* __restrict__ rank2) {
    int t = blockIdx.x * blockDim.x + threadIdx.x;
    if (t < E) {
        u32 u  = (u32)uid[t];
        u32 iN = (u32)(n_users + iid[t]);
        u32 su = 8u * (u & 3u), si = 8u * (iN & 3u);
        u32 r0 = atomicAdd(&degw[u >> 2],  1u << su);
        u32 r1 = atomicAdd(&degw[iN >> 2], 1u << si);
        r0 = (r0 >> su) & 0xffu;
        r1 = (r1 >> si) & 0xffu;
        rank2[t] = (u16)(r0 | (r1 << 8));   // deg < 256 (u8 counters)
    }
}

__global__ void dinv_kernel(const u8* __restrict__ deg8,
                            float* __restrict__ dinv, int n_nodes) {
    int t = blockIdx.x * blockDim.x + threadIdx.x;
    if (t < n_nodes) dinv[t] = rsqrtf((float)deg8[t] + 1e-8f);
}

// ---- prefix scan over u8 degrees: rp[i+1] = incl_sum(deg8[0..i]) ---------
__global__ void scan1_kernel(const u8* __restrict__ deg8,
                             u32* __restrict__ rp, u32* __restrict__ bsum, int n) {
    __shared__ u32 ts[256];
    int tid = threadIdx.x;
    int base = blockIdx.x * SCAN_CHUNK + tid * 8;
    u32 v[8];
    u32 s = 0;
    #pragma unroll
    for (int i = 0; i < 8; ++i) {
        v[i] = (base + i < n) ? (u32)deg8[base + i] : 0u;
        s += v[i];
    }
    ts[tid] = s;
    __syncthreads();
    for (int off = 1; off < 256; off <<= 1) {
        u32 a = (tid >= off) ? ts[tid - off] : 0u;
        __syncthreads();
        ts[tid] += a;
        __syncthreads();
    }
    u32 run = (tid > 0) ? ts[tid - 1] : 0u;
    #pragma unroll
    for (int i = 0; i < 8; ++i) {
        run += v[i];
        if (base + i < n) rp[base + i + 1] = run;
    }
    if (tid == 255) bsum[blockIdx.x] = ts[255];
}

__global__ void scan2_kernel(u32* __restrict__ bsum, int nb) {
    __shared__ u32 s[1024];
    int tid = threadIdx.x;
    s[tid] = (tid < nb) ? bsum[tid] : 0u;
    __syncthreads();
    for (int off = 1; off < 1024; off <<= 1) {
        u32 a = (tid >= off) ? s[tid - off] : 0u;
        __syncthreads();
        s[tid] += a;
        __syncthreads();
    }
    if (tid < nb) bsum[tid] = (tid == 0) ? 0u : s[tid - 1];
}

__global__ void scan3_kernel(u32* __restrict__ rp,
                             const u32* __restrict__ bsum, int n) {
    int t = blockIdx.x * blockDim.x + threadIdx.x;
    if (t < n) rp[t + 1] += bsum[t / SCAN_CHUNK];
    if (t == 0) rp[0] = 0u;
}

// ---- atomic-free, XCD-sliced CSR fill ------------------------------------
__global__ void fill_sliced_kernel(const int* __restrict__ uid,
                                   const int* __restrict__ iid,
                                   const u16* __restrict__ rank2,
                                   const u32* __restrict__ rp,
                                   int E, int n_users, int shift,
                                   int* __restrict__ ci) {
    int slice = blockIdx.x & 7;
    int chunk = blockIdx.x >> 3;
    int e0   = chunk * FILL_EPB;
    int eend = min(E, e0 + FILL_EPB);
    for (int e = e0 + threadIdx.x; e < eend; e += BLK) {
        int u  = uid[e];
        int iN = n_users + iid[e];
        u32 rr = (u32)rank2[e];
        if ((u >> shift) == slice)  ci[rp[u]  + (rr & 0xffu)] = iN;
        if ((iN >> shift) == slice) ci[rp[iN] + (rr >> 8)]    = u;
    }
}

// ---- z0 = dinv * emb, bf16 [node][64] = 8 uint4 per 128B row --------------
__global__ void z0_full_kernel(const f32x4* __restrict__ uemb,
                               const f32x4* __restrict__ iemb,
                               const float* __restrict__ dinv,
                               uint4* __restrict__ z0,
                               int n_users, int n_nodes) {
    long long t = (long long)blockIdx.x * blockDim.x + threadIdx.x;
    if (t >= (long long)n_nodes * 8) return;
    int row = (int)(t >> 3);
    int j   = (int)(t & 7);
    const f32x4* src = (row < n_users)
                           ? uemb + (size_t)row * 16 + j * 2
                           : iemb + (size_t)(row - n_users) * 16 + j * 2;
    f32x4 p = __builtin_nontemporal_load(src);
    f32x4 q = __builtin_nontemporal_load(src + 1);
    float w = dinv[row];
    uint4 o;
    o.x = pack_bf2(w * p.x, w * p.y);
    o.y = pack_bf2(w * p.z, w * p.w);
    o.z = pack_bf2(w * q.x, w * q.y);
    o.w = pack_bf2(w * q.z, w * q.w);
    z0[(size_t)row * 8 + j] = o;
}

// ---- middle layers: dst = bf16( dinv^2 * sum_{c} src[c] ), 128B rows ------
// 8 lanes per row, one uint4 (8 bf16) per lane per edge: every gather is one
// fully-used, aligned 128B TCC line.
__global__ void spmm_mid64(const u32* __restrict__ rp,
                           const int* __restrict__ ci,
                           const float* __restrict__ dinv,
                           const uint4* __restrict__ src,
                           uint4* __restrict__ dst, int n_nodes) {
    long long t = (long long)blockIdx.x * blockDim.x + threadIdx.x;
    int row = (int)(t >> 3);
    if (row >= n_nodes) return;
    int j = (int)(t & 7);
    const uint4* sp = src + j;
    u32 k = rp[row], end = rp[row + 1];
    float a[8] = {0.f, 0.f, 0.f, 0.f, 0.f, 0.f, 0.f, 0.f};
    for (; k + 3 < end; k += 4) {
        int c0 = ci[k], c1 = ci[k + 1], c2 = ci[k + 2], c3 = ci[k + 3];
        uint4 w0 = sp[(size_t)c0 * 8];
        uint4 w1 = sp[(size_t)c1 * 8];
        uint4 w2 = sp[(size_t)c2 * 8];
        uint4 w3 = sp[(size_t)c3 * 8];
        unpack_acc(w0, a); unpack_acc(w1, a);
        unpack_acc(w2, a); unpack_acc(w3, a);
    }
    for (; k < end; ++k) {
        uint4 w0 = sp[(size_t)ci[k] * 8];
        unpack_acc(w0, a);
    }
    float dr = dinv[row];
    float s = dr * dr;
    uint4 o;
    o.x = pack_bf2(s * a[0], s * a[1]);
    o.y = pack_bf2(s * a[2], s * a[3]);
    o.z = pack_bf2(s * a[4], s * a[5]);
    o.w = pack_bf2(s * a[6], s * a[7]);
    dst[(size_t)row * 8 + j] = o;
}

// ---- layer 3 + fused epilogue (normal loads, NT out stores) ---------------
__global__ void spmm_final64(const u32* __restrict__ rp,
                             const int* __restrict__ ci,
                             const float* __restrict__ dinv,
                             const uint4* __restrict__ z2,
                             const uint4* __restrict__ z1,
                             const uint4* __restrict__ z0,
                             f32x4* __restrict__ out, int n_nodes) {
    long long t = (long long)blockIdx.x * blockDim.x + threadIdx.x;
    int row = (int)(t >> 3);
    if (row >= n_nodes) return;
    int j = (int)(t & 7);
    const uint4* sp = z2 + j;
    u32 k = rp[row], end = rp[row + 1];
    float a[8] = {0.f, 0.f, 0.f, 0.f, 0.f, 0.f, 0.f, 0.f};
    for (; k + 3 < end; k += 4) {
        int c0 = ci[k], c1 = ci[k + 1], c2 = ci[k + 2], c3 = ci[k + 3];
        uint4 w0 = sp[(size_t)c0 * 8];
        uint4 w1 = sp[(size_t)c1 * 8];
        uint4 w2 = sp[(size_t)c2 * 8];
        uint4 w3 = sp[(size_t)c3 * 8];
        unpack_acc(w0, a); unpack_acc(w1, a);
        unpack_acc(w2, a); unpack_acc(w3, a);
    }
    for (; k < end; ++k) {
        uint4 w0 = sp[(size_t)ci[k] * 8];
        unpack_acc(w0, a);
    }
    float dr = dinv[row];
    float inv = 1.0f / dr;

    float v0[8], v1[8], v2[8];
    unpack8(z0[(size_t)row * 8 + j], v0);
    unpack8(z1[(size_t)row * 8 + j], v1);
    unpack8(z2[(size_t)row * 8 + j], v2);

    float r[8];
    #pragma unroll
    for (int i = 0; i < 8; ++i)
        r[i] = 0.25f * ((v0[i] + v1[i] + v2[i]) * inv + dr * a[i]);

    size_t ob = (size_t)row * 16 + j * 2;
    f32x4 lo = {r[0], r[1], r[2], r[3]};
    f32x4 hi = {r[4], r[5], r[6], r[7]};
    __builtin_nontemporal_store(lo, out + ob);
    __builtin_nontemporal_store(hi, out + ob + 1);
}

// ---------------------------------------------------------------------------
extern "C" void kernel_launch(void* const* d_in, const int* in_sizes, int n_in,
                              void* d_out, int out_size, void* d_ws, size_t ws_size,
                              hipStream_t stream) {
    const float* uemb = (const float*)d_in[0];
    const float* iemb = (const float*)d_in[1];
    const int*   uid  = (const int*)d_in[2];
    const int*   iid  = (const int*)d_in[3];

    const int d = 64;
    int n_users = in_sizes[0] / d;
    int n_items = in_sizes[1] / d;
    int E       = in_sizes[2];
    int n_nodes = n_users + n_items;
    long long nnz = 2LL * E;

    auto align256 = [](size_t x) { return (x + 255) & ~(size_t)255; };
    size_t deg_b  = align256((size_t)n_nodes + 4);       // u8 counters
    size_t rp_b   = align256((size_t)(n_nodes + 1) * 4);
    size_t dinv_b = align256((size_t)n_nodes * 4);
    size_t ci_b   = align256((size_t)nnz * 4);
    size_t rk_b   = align256((size_t)E * 2);             // u16 ranks
    size_t bs_b   = align256(4096 * 4);
    size_t z_b    = align256((size_t)n_nodes * 128);     // 64 bf16 per row

    char* p = (char*)d_ws;
    u32*   degw  = (u32*)p;    p += deg_b;
    u32*   rp    = (u32*)p;    p += rp_b;
    float* dinv  = (float*)p;  p += dinv_b;
    int*   ci    = (int*)p;    p += ci_b;
    u16*   rank2 = (u16*)p;    p += rk_b;
    u32*   bsum  = (u32*)p;    p += bs_b;
    uint4* z0    = (uint4*)p;  p += z_b;
    uint4* z1    = (uint4*)p;  p += z_b;
    uint4* z2    = (uint4*)p;

    // node-range slice shift for fill: slice = row >> shift in [0,8)
    int shift = 0;
    while (((n_nodes - 1) >> shift) >= 8) shift++;

    // ---- degrees (u8, + per-edge ranks), dinv ----
    hipMemsetAsync(degw, 0, (size_t)n_nodes + 4, stream);
    deg_rank_kernel<<<nblk(E), BLK, 0, stream>>>(uid, iid, E, n_users, degw, rank2);
    dinv_kernel<<<nblk(n_nodes), BLK, 0, stream>>>((const u8*)degw, dinv, n_nodes);

    // ---- prefix scan deg8 -> rp ----
    int nb = (n_nodes + SCAN_CHUNK - 1) / SCAN_CHUNK;
    scan1_kernel<<<nb, 256, 0, stream>>>((const u8*)degw, rp, bsum, n_nodes);
    scan2_kernel<<<1, 1024, 0, stream>>>(bsum, nb);
    scan3_kernel<<<nblk(n_nodes), BLK, 0, stream>>>(rp, bsum, n_nodes);

    // ---- atomic-free XCD-sliced CSR fill ----
    int nchunks = (E + FILL_EPB - 1) / FILL_EPB;
    fill_sliced_kernel<<<nchunks * 8, BLK, 0, stream>>>(
        uid, iid, rank2, rp, E, n_users, shift, ci);

    // ---- full-width bf16 pipeline: z0, two mids, fused final ----
    long long nt = (long long)n_nodes * 8;
    z0_full_kernel<<<nblk(nt), BLK, 0, stream>>>(
        (const f32x4*)uemb, (const f32x4*)iemb, dinv, z0, n_users, n_nodes);
    spmm_mid64<<<nblk(nt), BLK, 0, stream>>>(rp, ci, dinv, z0, z1, n_nodes);
    spmm_mid64<<<nblk(nt), BLK, 0, stream>>>(rp, ci, dinv, z1, z2, n_nodes);
    spmm_final64<<<nblk(nt), BLK, 0, stream>>>(rp, ci, dinv, z2, z1, z0,
                                               (f32x4*)d_out, n_nodes);
}